// Round 5
// baseline (385.792 us; speedup 1.0000x reference)
//
#include <hip/hip_runtime.h>
#include <hip/hip_bf16.h>
#include <math.h>

// Shapes (compile-time)
#define N_TOT 16384   // B*T
#define AG 8
#define OBSD 256
#define SD 512
#define NACT 32
#define ED 64
#define HYP 256

// ---------------- bf16 helpers / MFMA types ----------------
typedef __attribute__((ext_vector_type(8))) short bf16x8;   // 8 bf16 (4 VGPRs)
typedef __attribute__((ext_vector_type(4))) float f32x4;

__device__ __forceinline__ unsigned short f2bf(float f) {
    unsigned u = __float_as_uint(f);
    u += 0x7fffu + ((u >> 16) & 1u);          // round-to-nearest-even
    return (unsigned short)(u >> 16);
}
__device__ __forceinline__ float bf2f(unsigned short h) {
    return __uint_as_float(((unsigned)h) << 16);
}
#define MFMA16(a,b,c) __builtin_amdgcn_mfma_f32_16x16x32_bf16((a),(b),(c),0,0,0)
#define FRAG(p) (*(const bf16x8*)(p))

// ---------------- ws layout (bytes, 16B aligned) ----------------
#define WC_OFF     0u            // [192][264] bf16 (Wqkv @ Wobs folded)      101376
#define WCATC_OFF  101376u       // [16][640][40] bf16, K-chunked+padded      819200
#define WH1BC_OFF  920576u       // [4][512][72] bf16, K-chunked+padded       294912
#define WHFB_OFF   1215488u      // [64][264] bf16                            33792
#define ACTTAB_OFF 1249280u      // [32][192] f32                             24576
#define WQEFF_OFF  1273856u      // [192] f32
#define BIASQ_OFF  1274624u      // [192] f32
#define WEFF_OFF   1275392u      // [64] f32
#define CATT_OFF   1275648u      // [1] f32 (+pad)
#define ATT_OFF    1275712u      // [16384*8] f32                             524288
#define QKV_OFF    1800000u      // [131072][200] bf16                        52428800
#define WS_NEED    54228800u

// ===========================================================================
// Prep: weight conversion + algebraic folding. Wcat/Wh1b stored pre-chunked
// and pre-padded so kernel staging is a flat coalesced uint4 copy.
// ===========================================================================
__global__ __launch_bounds__(256) void k_prep(
    const float* __restrict__ W_obs, const float* __restrict__ W_act,
    const float* __restrict__ W_q,   const float* __restrict__ b_obs,
    const float* __restrict__ b_act, const float* __restrict__ b_q,
    const float* __restrict__ Wqkv,  const float* __restrict__ bqkv,
    const float* __restrict__ Wo,    const float* __restrict__ bo,
    const float* __restrict__ Wa2q,  const float* __restrict__ ba2q,
    const float* __restrict__ Wh1a, const float* __restrict__ Whfa,
    const float* __restrict__ Wv1,  const float* __restrict__ Wb1,
    const float* __restrict__ Wh1b, const float* __restrict__ Whfb,
    unsigned char* __restrict__ ws)
{
    unsigned short* wc    = (unsigned short*)(ws + WC_OFF);
    unsigned short* wcatc = (unsigned short*)(ws + WCATC_OFF);
    unsigned short* wh1bc = (unsigned short*)(ws + WH1BC_OFF);
    unsigned short* whfb  = (unsigned short*)(ws + WHFB_OFF);
    float* acttab = (float*)(ws + ACTTAB_OFF);
    float* wqeff  = (float*)(ws + WQEFF_OFF);
    float* biasq  = (float*)(ws + BIASQ_OFF);
    float* weff   = (float*)(ws + WEFF_OFF);
    float* catt   = (float*)(ws + CATT_OFF);

    const int TOT = 409600 + 147456 + 16896 + 49152 + 6144 + 192 + 192 + 64 + 1;
    for (int i = blockIdx.x * 256 + threadIdx.x; i < TOT; i += gridDim.x * 256) {
        int j = i;
        if (j < 409600) {                       // wcatc [16][640][40]
            int s = j / 25600, r2 = j - s * 25600;
            int row = r2 / 40, c = r2 - row * 40;
            float v = 0.f;
            if (c < 32) {
                int k = s * 32 + c;
                if (row < 256)      v = Wh1a[row * 512 + k];
                else if (row < 512) v = Whfa[(row - 256) * 512 + k];
                else if (row < 576) v = Wv1[(row - 512) * 512 + k];
                else                v = Wb1[(row - 576) * 512 + k];
            }
            wcatc[j] = f2bf(v);
        } else if ((j -= 409600) < 147456) {    // wh1bc [4][512][72]
            int c4 = j / 36864, r2 = j - c4 * 36864;
            int row = r2 / 72, c = r2 - row * 72;
            wh1bc[j] = f2bf(c < 64 ? Wh1b[row * 256 + c4 * 64 + c] : 0.f);
        } else if ((j -= 147456) < 16896) {     // whfb [64][264]
            int r = j / 264, c = j - r * 264;
            whfb[j] = f2bf(c < 256 ? Whfb[r * 256 + c] : 0.f);
        } else if ((j -= 16896) < 49152) {      // Wc = Wqkv @ Wobs : [192][264]
            int r = j >> 8, c = j & 255;
            float s = 0.f;
            #pragma unroll 8
            for (int e = 0; e < 64; ++e) s += Wqkv[r * 64 + e] * W_obs[e * 256 + c];
            wc[r * 264 + c] = f2bf(s);
        } else if ((j -= 49152) < 6144) {       // acttab[act][r]
            int r = j >> 5, act = j & 31;
            float s = 0.f;
            #pragma unroll 8
            for (int e = 0; e < 64; ++e) s += Wqkv[r * 64 + e] * W_act[e * 32 + act];
            acttab[act * 192 + r] = s;
        } else if ((j -= 6144) < 192) {         // wqeff
            float s = 0.f;
            #pragma unroll 8
            for (int e = 0; e < 64; ++e) s += Wqkv[j * 64 + e] * W_q[e];
            wqeff[j] = s;
        } else if ((j -= 192) < 192) {          // biasq
            float s = bqkv[j];
            #pragma unroll 8
            for (int e = 0; e < 64; ++e)
                s += Wqkv[j * 64 + e] * (b_obs[e] + b_act[e] + b_q[e]);
            biasq[j] = s;
        } else if ((j -= 192) < 64) {           // weff
            float s = 0.f;
            #pragma unroll 8
            for (int e2 = 0; e2 < 64; ++e2) s += Wa2q[e2] * Wo[e2 * 64 + j];
            weff[j] = s;
        } else {                                // catt
            float s = ba2q[0];
            #pragma unroll 8
            for (int e2 = 0; e2 < 64; ++e2) s += bo[e2] * Wa2q[e2];
            catt[0] = s;
        }
    }
}

// ===========================================================================
// K1a: qkv GEMM. M=131072 (n,a)-rows, N=192, K=256. 2048 blocks x 64 rows.
// Wc fragments in registers; pure HBM stream, one barrier per block.
// ===========================================================================
__global__ __launch_bounds__(256, 2) void k_qkv(
    const float* __restrict__ agent_qs,
    const float* __restrict__ observations,
    const int*   __restrict__ actions,
    const unsigned char* __restrict__ ws_w,
    unsigned short* __restrict__ qkv_out)
{
    __shared__ __align__(16) unsigned short s_obs[64 * 264];   // 33792 B
    __shared__ __align__(16) float s_att[32 * 192];            // 24576 B
    __shared__ float s_biasq[192], s_wqeff[192], s_qs[64];
    __shared__ int   s_acts[64];

    const int t = threadIdx.x;
    const int w = t >> 6, lane = t & 63, m = lane & 15, q = lane >> 4;
    const int R0 = blockIdx.x * 64;

    const unsigned short* wc = (const unsigned short*)(ws_w + WC_OFF);
    const float* acttab_g = (const float*)(ws_w + ACTTAB_OFF);
    const float* wqeff_g  = (const float*)(ws_w + WQEFF_OFF);
    const float* biasq_g  = (const float*)(ws_w + BIASQ_OFF);

    for (int i = t; i < 1536; i += 256)
        ((float4*)s_att)[i] = ((const float4*)acttab_g)[i];
    if (t < 192) { s_biasq[t] = biasq_g[t]; s_wqeff[t] = wqeff_g[t]; }
    if (t < 64)  { s_acts[t] = actions[R0 + t]; s_qs[t] = agent_qs[R0 + t]; }

    // Wc fragments in registers: wave w owns col-tiles w*3..w*3+2
    bf16x8 wf[3][8];
    #pragma unroll
    for (int ctl = 0; ctl < 3; ++ctl)
        #pragma unroll
        for (int kc = 0; kc < 8; ++kc)
            wf[ctl][kc] = FRAG(&wc[((w * 3 + ctl) * 16 + m) * 264 + kc * 32 + q * 8]);

    // stage obs tile (64 rows x 256 f32 -> bf16 LDS)
    const float4* obs4 = (const float4*)observations;
    #pragma unroll
    for (int c = 0; c < 16; ++c) {
        int i = t + c * 256, row = i >> 6, x4 = i & 63;
        float4 f = obs4[(size_t)(R0 + row) * 64 + x4];
        ushort4 h = { f2bf(f.x), f2bf(f.y), f2bf(f.z), f2bf(f.w) };
        *(ushort4*)&s_obs[row * 264 + x4 * 4] = h;
    }
    __syncthreads();

    f32x4 acc[4][3];
    #pragma unroll
    for (int rt = 0; rt < 4; ++rt)
        #pragma unroll
        for (int c2 = 0; c2 < 3; ++c2) acc[rt][c2] = (f32x4){0.f,0.f,0.f,0.f};
    #pragma unroll
    for (int kc = 0; kc < 8; ++kc) {
        bf16x8 af[4];
        #pragma unroll
        for (int rt = 0; rt < 4; ++rt)
            af[rt] = FRAG(&s_obs[(rt * 16 + m) * 264 + kc * 32 + q * 8]);
        #pragma unroll
        for (int ctl = 0; ctl < 3; ++ctl)
            #pragma unroll
            for (int rt = 0; rt < 4; ++rt)
                acc[rt][ctl] = MFMA16(af[rt], wf[ctl][kc], acc[rt][ctl]);
    }

    // epilogue -> global qkv [R][200] bf16
    #pragma unroll
    for (int ctl = 0; ctl < 3; ++ctl) {
        int j = (w * 3 + ctl) * 16 + m;
        float bq = s_biasq[j], wq = s_wqeff[j];
        #pragma unroll
        for (int rt = 0; rt < 4; ++rt)
            #pragma unroll
            for (int r = 0; r < 4; ++r) {
                int row = rt * 16 + q * 4 + r;
                float v = acc[rt][ctl][r] + bq
                        + s_att[s_acts[row] * 192 + j] + s_qs[row] * wq;
                qkv_out[(size_t)(R0 + row) * 200 + j] = f2bf(v);
            }
    }
}

// ===========================================================================
// K1b: attention from qkv -> attended[N,A]. 2048 blocks x 8 n, 256 threads.
// ===========================================================================
__global__ __launch_bounds__(256) void k_att(
    const unsigned char* __restrict__ ws, float* __restrict__ attended)
{
    __shared__ __align__(16) unsigned short s_q[64 * 200];  // 25600 B
    __shared__ float s_vw[8][8][4];
    __shared__ float s_part[8][8][4];
    __shared__ float s_weff[64];

    const int t = threadIdx.x;
    const int nb0 = blockIdx.x * 8;

    const unsigned short* qkv = (const unsigned short*)(ws + QKV_OFF);
    const float* weff_g = (const float*)(ws + WEFF_OFF);
    const float* catt_g = (const float*)(ws + CATT_OFF);

    // stage 64 rows x 200 bf16 (flat copy incl. pad)
    const uint4* src = (const uint4*)(qkv + (size_t)nb0 * 8 * 200);
    #pragma unroll
    for (int c = 0; c < 7; ++c) {
        int i = t + c * 256;
        if (i < 1600) ((uint4*)s_q)[i] = src[i];
    }
    if (t < 64) s_weff[t] = weff_g[t];
    __syncthreads();

    // vw[n][b][h] = dot(v, weff_h)
    {
        int n = t >> 5, b = (t >> 2) & 7, h = t & 3;
        bf16x8 va = FRAG(&s_q[(n * 8 + b) * 200 + 128 + h * 16]);
        bf16x8 vb = FRAG(&s_q[(n * 8 + b) * 200 + 128 + h * 16 + 8]);
        float s = 0.f;
        #pragma unroll
        for (int d = 0; d < 8; ++d)
            s += bf2f((unsigned short)va[d]) * s_weff[h * 16 + d]
               + bf2f((unsigned short)vb[d]) * s_weff[h * 16 + 8 + d];
        s_vw[n][b][h] = s;
    }
    __syncthreads();

    // softmax + combine: thread = (n,h,a)
    {
        int n = t >> 5, h = (t >> 3) & 3, a = t & 7;
        int qrow = n * 8 + a;
        float qv[16];
        {
            bf16x8 qa = FRAG(&s_q[qrow * 200 + h * 16]);
            bf16x8 qb = FRAG(&s_q[qrow * 200 + h * 16 + 8]);
            #pragma unroll
            for (int d = 0; d < 8; ++d) {
                qv[d]     = bf2f((unsigned short)qa[d]);
                qv[d + 8] = bf2f((unsigned short)qb[d]);
            }
        }
        float sc[8], mx = -1e30f;
        #pragma unroll
        for (int b = 0; b < 8; ++b) {
            bf16x8 ka = FRAG(&s_q[(n * 8 + b) * 200 + 64 + h * 16]);
            bf16x8 kb = FRAG(&s_q[(n * 8 + b) * 200 + 64 + h * 16 + 8]);
            float s = 0.f;
            #pragma unroll
            for (int d = 0; d < 8; ++d)
                s += qv[d] * bf2f((unsigned short)ka[d])
                   + qv[d + 8] * bf2f((unsigned short)kb[d]);
            sc[b] = s * 0.25f;
            mx = fmaxf(mx, sc[b]);
        }
        float sum = 0.f;
        #pragma unroll
        for (int b = 0; b < 8; ++b) { sc[b] = __expf(sc[b] - mx); sum += sc[b]; }
        float inv = 1.f / sum, s = 0.f;
        #pragma unroll
        for (int b = 0; b < 8; ++b) s += sc[b] * inv * s_vw[n][b][h];
        s_part[n][a][h] = s;
    }
    __syncthreads();
    if (t < 64) {
        int n = t >> 3, a = t & 7;
        float y = catt_g[0];
        #pragma unroll
        for (int h = 0; h < 4; ++h) y += s_part[n][a][h];
        attended[(size_t)(nb0 + n) * 8 + a] = y;
    }
}

// ===========================================================================
// K2: fused hypernet, despilled. 256 blocks x 64 rows, 512 threads.
// L1: K=32 chunks double-buffered, wave owns 5 col-tiles for ALL 4 row-tiles.
// L2a: wave = (rt-pair, e-tile), hid in registers. All weights via flat-copy
// staging from pre-chunked ws layouts.
// ===========================================================================
__global__ __launch_bounds__(512, 2) void k_hx(
    const float* __restrict__ states,
    const float* __restrict__ bh1a, const float* __restrict__ bhfa,
    const float* __restrict__ bv1,  const float* __restrict__ bb1g,
    const float* __restrict__ Wv2,
    const float* __restrict__ bh1b, const float* __restrict__ bhfb,
    const float* __restrict__ bv2,
    const unsigned char* __restrict__ ws, float* __restrict__ out)
{
    __shared__ __align__(16) unsigned char smem[160256];
    // L1 regions
    unsigned short* Bb0 = (unsigned short*)(smem);            // [640][40]
    unsigned short* Bb1 = (unsigned short*)(smem + 51200);
    unsigned short* Ab0 = (unsigned short*)(smem + 102400);   // [64][40]
    unsigned short* Ab1 = (unsigned short*)(smem + 107520);
    // L2 regions (alias; valid after L1 completes)
    unsigned short* Wb   = (unsigned short*)(smem);           // [512][72] / whfb [64][264]
    unsigned short* h1a  = (unsigned short*)(smem + 73728);   // [64][264]
    unsigned short* hfa  = (unsigned short*)(smem + 107520);  // [64][264]
    unsigned short* b1l  = (unsigned short*)(smem + 141312);  // [64][68]
    float* vred  = (float*)(smem + 150016);                   // [64][2][16]
    float* s_aq  = (float*)(smem + 158208);                   // [64][8]
    float* s_red = (float*)(smem + 73728);                    // [64][68] f32 (after L2a)

    const int t = threadIdx.x;
    const int w = t >> 6, lane = t & 63, m = lane & 15, q = lane >> 4;
    const int n0 = blockIdx.x * 64;

    const unsigned short* wcatc = (const unsigned short*)(ws + WCATC_OFF);
    const unsigned short* wh1bc = (const unsigned short*)(ws + WH1BC_OFF);
    const unsigned short* whfbg = (const unsigned short*)(ws + WHFB_OFF);
    const float* att = (const float*)(ws + ATT_OFF);

    // ---- stage L1 chunk 0 ----
    #pragma unroll
    for (int c = 0; c < 7; ++c) {
        int i = t + c * 512;
        if (i < 3200) ((uint4*)Bb0)[i] = ((const uint4*)wcatc)[i];
    }
    {
        int row = t >> 3, xf = t & 7;
        float4 f = *(const float4*)(states + (size_t)(n0 + row) * 512 + xf * 4);
        ushort4 h = { f2bf(f.x), f2bf(f.y), f2bf(f.z), f2bf(f.w) };
        *(ushort4*)&Ab0[row * 40 + xf * 4] = h;
    }
    __syncthreads();

    // ---- L1 pipelined loop: 16 chunks of K=32 ----
    f32x4 acc[5][4];
    #pragma unroll
    for (int c2 = 0; c2 < 5; ++c2)
        #pragma unroll
        for (int rt = 0; rt < 4; ++rt) acc[c2][rt] = (f32x4){0.f,0.f,0.f,0.f};

    for (int s = 0; s < 16; ++s) {
        unsigned short* Bc = (s & 1) ? Bb1 : Bb0;
        unsigned short* Ac = (s & 1) ? Ab1 : Ab0;
        unsigned short* Bn = (s & 1) ? Bb0 : Bb1;
        unsigned short* An = (s & 1) ? Ab0 : Ab1;
        uint4 pb[7]; float4 pa;
        if (s < 15) {
            #pragma unroll
            for (int c = 0; c < 7; ++c) {
                int i = t + c * 512;
                if (i < 3200) pb[c] = ((const uint4*)wcatc)[(s + 1) * 3200 + i];
            }
            pa = *(const float4*)(states + (size_t)(n0 + (t >> 3)) * 512
                                  + (s + 1) * 32 + (t & 7) * 4);
        }
        // MFMA chunk s
        bf16x8 af[4];
        #pragma unroll
        for (int rt = 0; rt < 4; ++rt)
            af[rt] = FRAG(&Ac[(rt * 16 + m) * 40 + q * 8]);
        #pragma unroll
        for (int ctl = 0; ctl < 5; ++ctl) {
            int ct = w * 5 + ctl;
            bf16x8 b = FRAG(&Bc[(ct * 16 + m) * 40 + q * 8]);
            #pragma unroll
            for (int rt = 0; rt < 4; ++rt)
                acc[ctl][rt] = MFMA16(af[rt], b, acc[ctl][rt]);
        }
        if (s < 15) {
            #pragma unroll
            for (int c = 0; c < 7; ++c) {
                int i = t + c * 512;
                if (i < 3200) ((uint4*)Bn)[i] = pb[c];
            }
            ushort4 h = { f2bf(pa.x), f2bf(pa.y), f2bf(pa.z), f2bf(pa.w) };
            *(ushort4*)&An[(t >> 3) * 40 + (t & 7) * 4] = h;
        }
        __syncthreads();
    }

    // ---- L1 epilogue (regions overlap dead L1 buffers; post-barrier) ----
    {
        float vp[16];
        #pragma unroll
        for (int i = 0; i < 16; ++i) vp[i] = 0.f;
        #pragma unroll
        for (int ctl = 0; ctl < 5; ++ctl) {
            int ct = w * 5 + ctl, jj = ct * 16 + m;
            if (ct < 16) {
                float bb = bh1a[jj];
                #pragma unroll
                for (int rt = 0; rt < 4; ++rt)
                    #pragma unroll
                    for (int r = 0; r < 4; ++r)
                        h1a[(rt * 16 + q * 4 + r) * 264 + jj] =
                            f2bf(fmaxf(acc[ctl][rt][r] + bb, 0.f));
            } else if (ct < 32) {
                float bb = bhfa[jj - 256];
                #pragma unroll
                for (int rt = 0; rt < 4; ++rt)
                    #pragma unroll
                    for (int r = 0; r < 4; ++r)
                        hfa[(rt * 16 + q * 4 + r) * 264 + (jj - 256)] =
                            f2bf(fmaxf(acc[ctl][rt][r] + bb, 0.f));
            } else if (ct < 36) {
                float bb = bv1[jj - 512], wv = Wv2[jj - 512];
                #pragma unroll
                for (int rt = 0; rt < 4; ++rt)
                    #pragma unroll
                    for (int r = 0; r < 4; ++r)
                        vp[rt * 4 + r] += fmaxf(acc[ctl][rt][r] + bb, 0.f) * wv;
            } else {
                float bb = bb1g[jj - 576];
                #pragma unroll
                for (int rt = 0; rt < 4; ++rt)
                    #pragma unroll
                    for (int r = 0; r < 4; ++r)
                        b1l[(rt * 16 + q * 4 + r) * 68 + (jj - 576)] =
                            f2bf(acc[ctl][rt][r] + bb);
            }
        }
        if (w == 6 || w == 7) {
            #pragma unroll
            for (int rt = 0; rt < 4; ++rt)
                #pragma unroll
                for (int r = 0; r < 4; ++r)
                    vred[(rt * 16 + q * 4 + r) * 32 + (w - 6) * 16 + m] = vp[rt * 4 + r];
        }
    }
    s_aq[t] = att[(size_t)n0 * 8 + t];
    // stage L2a chunk 0 (disjoint from epilogue target regions)
    #pragma unroll
    for (int c = 0; c < 9; ++c) {
        int i = t + c * 512;
        ((uint4*)Wb)[i] = ((const uint4*)wh1bc)[i];
    }
    __syncthreads();

    // ---- L2a: w1 = h1a @ Wh1b^T. wave = (rtp = w>>2, ch = w&3) ----
    const int ch = w & 3, rtp = w >> 2;
    f32x4 acc2[8][2];
    #pragma unroll
    for (int a = 0; a < 8; ++a)
        #pragma unroll
        for (int rtl = 0; rtl < 2; ++rtl) acc2[a][rtl] = (f32x4){0.f,0.f,0.f,0.f};

    for (int c4 = 0; c4 < 4; ++c4) {
        if (c4 > 0) {
            #pragma unroll
            for (int c = 0; c < 9; ++c) {
                int i = t + c * 512;
                ((uint4*)Wb)[i] = ((const uint4*)wh1bc)[c4 * 4608 + i];
            }
            __syncthreads();
        }
        #pragma unroll
        for (int kc2 = 0; kc2 < 2; ++kc2) {
            bf16x8 af2[2];
            #pragma unroll
            for (int rtl = 0; rtl < 2; ++rtl)
                af2[rtl] = FRAG(&h1a[((rtp * 2 + rtl) * 16 + m) * 264
                                     + c4 * 64 + kc2 * 32 + q * 8]);
            #pragma unroll
            for (int a = 0; a < 8; ++a) {
                bf16x8 b = FRAG(&Wb[(a * 64 + ch * 16 + m) * 72 + kc2 * 32 + q * 8]);
                #pragma unroll
                for (int rtl = 0; rtl < 2; ++rtl)
                    acc2[a][rtl] = MFMA16(af2[rtl], b, acc2[a][rtl]);
            }
        }
        __syncthreads();
    }

    // hid in registers: hid[rtl][r] = sum_a aq[row][a] * |w1 + b|
    float bb1b[8];
    #pragma unroll
    for (int a = 0; a < 8; ++a) bb1b[a] = bh1b[a * 64 + ch * 16 + m];
    float hid[2][4];
    #pragma unroll
    for (int rtl = 0; rtl < 2; ++rtl)
        #pragma unroll
        for (int r = 0; r < 4; ++r) {
            int row = (rtp * 2 + rtl) * 16 + q * 4 + r;
            float4 a0 = *(const float4*)&s_aq[row * 8];
            float4 a1 = *(const float4*)&s_aq[row * 8 + 4];
            float hh = a0.x * fabsf(acc2[0][rtl][r] + bb1b[0])
                     + a0.y * fabsf(acc2[1][rtl][r] + bb1b[1])
                     + a0.z * fabsf(acc2[2][rtl][r] + bb1b[2])
                     + a0.w * fabsf(acc2[3][rtl][r] + bb1b[3])
                     + a1.x * fabsf(acc2[4][rtl][r] + bb1b[4])
                     + a1.y * fabsf(acc2[5][rtl][r] + bb1b[5])
                     + a1.z * fabsf(acc2[6][rtl][r] + bb1b[6])
                     + a1.w * fabsf(acc2[7][rtl][r] + bb1b[7]);
            hid[rtl][r] = hh;
        }

    // ---- L2b: w_f = |hfa @ Whfb^T + b|; elu; product ----
    #pragma unroll
    for (int c = 0; c < 5; ++c) {               // stage whfb [64][264] flat
        int i = t + c * 512;
        if (i < 2112) ((uint4*)Wb)[i] = ((const uint4*)whfbg)[i];
    }
    __syncthreads();
    f32x4 wfacc[2] = { {0.f,0.f,0.f,0.f}, {0.f,0.f,0.f,0.f} };
    #pragma unroll
    for (int kc = 0; kc < 8; ++kc) {
        bf16x8 b = FRAG(&Wb[(ch * 16 + m) * 264 + kc * 32 + q * 8]);
        #pragma unroll
        for (int rtl = 0; rtl < 2; ++rtl) {
            bf16x8 a = FRAG(&hfa[((rtp * 2 + rtl) * 16 + m) * 264 + kc * 32 + q * 8]);
            wfacc[rtl] = MFMA16(a, b, wfacc[rtl]);
        }
    }
    {
        int e = ch * 16 + m;
        float bbf = bhfb[e];
        #pragma unroll
        for (int rtl = 0; rtl < 2; ++rtl)
            #pragma unroll
            for (int r = 0; r < 4; ++r) {
                int row = (rtp * 2 + rtl) * 16 + q * 4 + r;
                float wfv = fabsf(wfacc[rtl][r] + bbf);
                float hv = hid[rtl][r] + bf2f(b1l[row * 68 + e]);
                hv = (hv > 0.f) ? hv : expm1f(hv);
                s_red[row * 68 + e] = wfv * hv;   // disjoint from Wb region
            }
    }
    __syncthreads();
    if (t < 64) {
        float y = bv2[0];
        #pragma unroll
        for (int i = 0; i < 32; ++i) y += vred[t * 32 + i];
        #pragma unroll
        for (int e = 0; e < 64; ++e) y += s_red[t * 68 + e];
        out[n0 + t] = y;
    }
}

// ===========================================================================
// Fallback (round-1, validated) kernels — used if ws_size is too small.
// ===========================================================================
#define NBF 16
__global__ __launch_bounds__(256) void k_enc_attn_fb(
    const float* __restrict__ agent_qs, const float* __restrict__ observations,
    const int* __restrict__ actions,
    const float* __restrict__ W_obs, const float* __restrict__ b_obs,
    const float* __restrict__ W_act, const float* __restrict__ b_act,
    const float* __restrict__ W_q,   const float* __restrict__ b_q,
    const float* __restrict__ Wqkv,  const float* __restrict__ bqkv,
    const float* __restrict__ Wo,    const float* __restrict__ bo,
    const float* __restrict__ Wa2q,  const float* __restrict__ ba2q,
    float* __restrict__ attended)
{
    __shared__ __align__(16) float s_obs[AG][OBSD];
    __shared__ __align__(16) float s_x[AG][ED];
    __shared__ __align__(16) float s_qkv[AG][3*ED];
    __shared__ float s_p[4][AG][AG];
    __shared__ __align__(16) float s_o[AG][ED];
    const int n = blockIdx.x, t = threadIdx.x;
    { const float4* g = (const float4*)(observations + (size_t)n*(AG*OBSD));
      float4* s4 = (float4*)&s_obs[0][0];
      for (int i = 0; i < 2; ++i) s4[t + i*256] = g[t + i*256]; }
    __syncthreads();
    { const int e = t & 63, a0 = t >> 6;
      const float wq = W_q[e]; const float bias0 = b_obs[e]+b_act[e]+b_q[e];
      const float* wrow = W_obs + e*OBSD;
      for (int g = 0; g < 2; ++g) { const int a = a0 + g*4; float acc = 0.f;
        for (int k = 0; k < OBSD; k += 4) { const float4 wv = *(const float4*)(wrow+k);
          acc += wv.x*s_obs[a][k]+wv.y*s_obs[a][k+1]+wv.z*s_obs[a][k+2]+wv.w*s_obs[a][k+3]; }
        s_x[a][e] = acc + bias0 + W_act[e*NACT + actions[n*AG+a]] + agent_qs[n*AG+a]*wq; } }
    __syncthreads();
    for (int g = 0; g < 6; ++g) { const int i = t + g*256, a = i/192, j = i - a*192;
      const float* wrow = Wqkv + j*ED; float acc = bqkv[j];
      for (int k = 0; k < ED; k += 4) { const float4 wv = *(const float4*)(wrow+k);
        acc += wv.x*s_x[a][k]+wv.y*s_x[a][k+1]+wv.z*s_x[a][k+2]+wv.w*s_x[a][k+3]; }
      s_qkv[a][j] = acc; }
    __syncthreads();
    { const int h = t>>6, a = (t>>3)&7, b = t&7; float acc = 0.f;
      for (int d = 0; d < 16; ++d) acc += s_qkv[a][h*16+d]*s_qkv[b][64+h*16+d];
      s_p[h][a][b] = acc*0.25f; }
    __syncthreads();
    if (t < 32) { const int h = t>>3, a = t&7; float mm = -1e30f;
      for (int b = 0; b < 8; ++b) mm = fmaxf(mm, s_p[h][a][b]);
      float ex[8], sum = 0.f;
      for (int b = 0; b < 8; ++b) { ex[b] = __expf(s_p[h][a][b]-mm); sum += ex[b]; }
      for (int b = 0; b < 8; ++b) s_p[h][a][b] = ex[b]/sum; }
    __syncthreads();
    for (int g = 0; g < 2; ++g) { const int i = t+g*256, a = i>>6, c = i&63, h = c>>4;
      float acc = 0.f;
      for (int b = 0; b < 8; ++b) acc += s_p[h][a][b]*s_qkv[b][128+c];
      s_o[a][c] = acc; }
    __syncthreads();
    for (int g = 0; g < 2; ++g) { const int i = t+g*256, a = i>>6, e2 = i&63;
      const float* wrow = Wo + e2*ED; float acc = bo[e2];
      for (int k = 0; k < ED; k += 4) { const float4 wv = *(const float4*)(wrow+k);
        acc += wv.x*s_o[a][k]+wv.y*s_o[a][k+1]+wv.z*s_o[a][k+2]+wv.w*s_o[a][k+3]; }
      s_x[a][e2] = acc * Wa2q[e2]; }
    __syncthreads();
    if (t < 8) { float s = ba2q[0];
      for (int e2 = 0; e2 < 64; ++e2) s += s_x[t][e2];
      attended[n*AG+t] = s; }
}

__global__ __launch_bounds__(256) void k_mixer_fb(
    const float* __restrict__ states, const float* __restrict__ attended,
    const float* __restrict__ Wh1a, const float* __restrict__ bh1a,
    const float* __restrict__ Wh1b, const float* __restrict__ bh1b,
    const float* __restrict__ Whfa, const float* __restrict__ bhfa,
    const float* __restrict__ Whfb, const float* __restrict__ bhfb,
    const float* __restrict__ Wb1,  const float* __restrict__ bb1,
    const float* __restrict__ Wv1,  const float* __restrict__ bv1,
    const float* __restrict__ Wv2,  const float* __restrict__ bv2,
    float* __restrict__ out)
{
    __shared__ __align__(16) float s_st[NBF][SD];
    __shared__ __align__(16) float s_h[NBF][HYP];
    __shared__ __align__(16) float s_hid[NBF][ED];
    __shared__ __align__(16) float s_prod[NBF][ED];
    __shared__ __align__(16) float s_v[NBF][ED];
    __shared__ float s_aq[NBF][AG];
    const int n0 = blockIdx.x * NBF, t = threadIdx.x;
    { const float4* g = (const float4*)(states + (size_t)n0*SD);
      float4* s4 = (float4*)&s_st[0][0];
      for (int i = 0; i < 8; ++i) s4[t + i*256] = g[t + i*256];
      if (t < NBF*AG) ((float*)s_aq)[t] = attended[n0*AG + t]; }
    __syncthreads();
    { const float* wrow = Wh1a + t*SD; float acc[NBF];
      for (int n = 0; n < NBF; ++n) acc[n] = 0.f;
      for (int k = 0; k < SD; k += 4) { const float4 wv = *(const float4*)(wrow+k);
        for (int n = 0; n < NBF; ++n) { const float4 x = *(const float4*)(&s_st[n][k]);
          acc[n] += wv.x*x.x+wv.y*x.y+wv.z*x.z+wv.w*x.w; } }
      const float bb = bh1a[t];
      for (int n = 0; n < NBF; ++n) s_h[n][t] = fmaxf(acc[n]+bb, 0.f); }
    for (int g = 0; g < 4; ++g) { const int i = t+g*256, n = i>>6, e = i&63;
      const float* wrow = Wb1 + e*SD; float acc = bb1[e];
      for (int k = 0; k < SD; k += 4) { const float4 wv = *(const float4*)(wrow+k);
        const float4 x = *(const float4*)(&s_st[n][k]);
        acc += wv.x*x.x+wv.y*x.y+wv.z*x.z+wv.w*x.w; }
      s_hid[n][e] = acc; }
    __syncthreads();
    for (int g = 0; g < 2; ++g) { const int j = t+g*256;
      const float* wrow = Wh1b + j*HYP; float acc[NBF];
      for (int n = 0; n < NBF; ++n) acc[n] = 0.f;
      for (int k = 0; k < HYP; k += 4) { const float4 wv = *(const float4*)(wrow+k);
        for (int n = 0; n < NBF; ++n) { const float4 x = *(const float4*)(&s_h[n][k]);
          acc[n] += wv.x*x.x+wv.y*x.y+wv.z*x.z+wv.w*x.w; } }
      const float bb = bh1b[j]; const int a = j>>6, e = j&63;
      for (int n = 0; n < NBF; ++n)
        atomicAdd(&s_hid[n][e], s_aq[n][a]*fabsf(acc[n]+bb)); }
    __syncthreads();
    { const float* wrow = Whfa + t*SD; float acc[NBF];
      for (int n = 0; n < NBF; ++n) acc[n] = 0.f;
      for (int k = 0; k < SD; k += 4) { const float4 wv = *(const float4*)(wrow+k);
        for (int n = 0; n < NBF; ++n) { const float4 x = *(const float4*)(&s_st[n][k]);
          acc[n] += wv.x*x.x+wv.y*x.y+wv.z*x.z+wv.w*x.w; } }
      const float bb = bhfa[t];
      for (int n = 0; n < NBF; ++n) s_h[n][t] = fmaxf(acc[n]+bb, 0.f); }
    __syncthreads();
    for (int g = 0; g < 4; ++g) { const int i = t+g*256, n = i>>6, e = i&63;
      { const float* wrow = Whfb + e*HYP; float acc = bhfb[e];
        for (int k = 0; k < HYP; k += 4) { const float4 wv = *(const float4*)(wrow+k);
          const float4 x = *(const float4*)(&s_h[n][k]);
          acc += wv.x*x.x+wv.y*x.y+wv.z*x.z+wv.w*x.w; }
        float h = s_hid[n][e]; h = (h > 0.f) ? h : expm1f(h);
        s_prod[n][e] = fabsf(acc)*h; }
      { const float* wrow = Wv1 + e*SD; float acc = bv1[e];
        for (int k = 0; k < SD; k += 4) { const float4 wv = *(const float4*)(wrow+k);
          const float4 x = *(const float4*)(&s_st[n][k]);
          acc += wv.x*x.x+wv.y*x.y+wv.z*x.z+wv.w*x.w; }
        s_v[n][e] = fmaxf(acc, 0.f)*Wv2[e]; } }
    __syncthreads();
    if (t < NBF) { float y = bv2[0];
      for (int e = 0; e < ED; ++e) y += s_prod[t][e] + s_v[t][e];
      out[n0+t] = y; }
}

// ===========================================================================
extern "C" void kernel_launch(void* const* d_in, const int* in_sizes, int n_in,
                              void* d_out, int out_size, void* d_ws, size_t ws_size,
                              hipStream_t stream) {
    const float* agent_qs     = (const float*)d_in[0];
    const float* states       = (const float*)d_in[1];
    const float* observations = (const float*)d_in[2];
    const int*   actions      = (const int*)  d_in[3];
    const float* W_obs = (const float*)d_in[4];  const float* b_obs = (const float*)d_in[5];
    const float* W_act = (const float*)d_in[6];  const float* b_act = (const float*)d_in[7];
    const float* W_q   = (const float*)d_in[8];  const float* b_q   = (const float*)d_in[9];
    const float* Wqkv  = (const float*)d_in[10]; const float* bqkv  = (const float*)d_in[11];
    const float* Wo    = (const float*)d_in[12]; const float* bo    = (const float*)d_in[13];
    const float* Wa2q  = (const float*)d_in[14]; const float* ba2q  = (const float*)d_in[15];
    const float* Wh1a  = (const float*)d_in[16]; const float* bh1a  = (const float*)d_in[17];
    const float* Wh1b  = (const float*)d_in[18]; const float* bh1b  = (const float*)d_in[19];
    const float* Whfa  = (const float*)d_in[20]; const float* bhfa  = (const float*)d_in[21];
    const float* Whfb  = (const float*)d_in[22]; const float* bhfb  = (const float*)d_in[23];
    const float* Wb1   = (const float*)d_in[24]; const float* bb1   = (const float*)d_in[25];
    const float* Wv1   = (const float*)d_in[26]; const float* bv1   = (const float*)d_in[27];
    const float* Wv2   = (const float*)d_in[28]; const float* bv2   = (const float*)d_in[29];
    float* out = (float*)d_out;

    if (ws_size >= WS_NEED) {
        unsigned char* ws = (unsigned char*)d_ws;
        float* attended = (float*)(ws + ATT_OFF);
        unsigned short* qkv = (unsigned short*)(ws + QKV_OFF);
        k_prep<<<512, 256, 0, stream>>>(W_obs, W_act, W_q, b_obs, b_act, b_q,
                                        Wqkv, bqkv, Wo, bo, Wa2q, ba2q,
                                        Wh1a, Whfa, Wv1, Wb1, Wh1b, Whfb, ws);
        k_qkv<<<2048, 256, 0, stream>>>(agent_qs, observations, actions, ws, qkv);
        k_att<<<2048, 256, 0, stream>>>(ws, attended);
        k_hx<<<N_TOT / 64, 512, 0, stream>>>(states, bh1a, bhfa, bv1, bb1, Wv2,
                                             bh1b, bhfb, bv2, ws, out);
    } else {
        float* attended = (float*)d_ws;
        k_enc_attn_fb<<<N_TOT, 256, 0, stream>>>(agent_qs, observations, actions,
            W_obs, b_obs, W_act, b_act, W_q, b_q, Wqkv, bqkv, Wo, bo, Wa2q, ba2q, attended);
        k_mixer_fb<<<N_TOT / NBF, 256, 0, stream>>>(states, attended,
            Wh1a, bh1a, Wh1b, bh1b, Whfa, bhfa, Whfb, bhfb,
            Wb1, bb1, Wv1, bv1, Wv2, bv2, out);
    }
}